// Round 3
// baseline (1349.489 us; speedup 1.0000x reference)
//
#include <hip/hip_runtime.h>
#include <hip/hip_bf16.h>
#include <math.h>

// RWKV-7 TimeMix. R6: wkv7 2-rows-per-16-lane-group (ILP to hide DPP/LDS
// latency at the 1-wave/SIMD occupancy floor). Column data shared between
// the row pair; 96 blocks x 256 threads. cvtw fused into one launch.
// B=4 T=2048 C=768 H=12 N=64, LAYER_ID=1.

#define B_  4
#define T_  2048
#define C_  768
#define H_  12

typedef __attribute__((ext_vector_type(8))) short bf16x8;
typedef __attribute__((ext_vector_type(4))) float f32x4;

#define GLD16(gsrc, ldst)                                                     \
  __builtin_amdgcn_global_load_lds(                                           \
      (const __attribute__((address_space(1))) void*)(gsrc),                  \
      (__attribute__((address_space(3))) void*)(ldst), 16, 0, 0)

// ---- DPP helpers: sum across each 16-lane DPP row, all-VALU ----
template <int CTRL>
static __device__ __forceinline__ float row_ror_add(float v) {
  int t = __builtin_amdgcn_update_dpp(0, __float_as_int(v), CTRL, 0xF, 0xF, true);
  return v + __int_as_float(t);
}
static __device__ __forceinline__ float row_sum16(float v) {
  v = row_ror_add<0x128>(v);  // row_ror:8
  v = row_ror_add<0x124>(v);  // row_ror:4
  v = row_ror_add<0x122>(v);  // row_ror:2
  v = row_ror_add<0x121>(v);  // row_ror:1
  return v;                   // every lane in the 16-group holds the sum
}

static __device__ __forceinline__ float wave_sum64(float v) {
  v = row_sum16(v);
  v += __shfl_xor(v, 16);
  v += __shfl_xor(v, 32);
  return v;
}

static __device__ __forceinline__ short bf16b(float f) {
  __hip_bfloat16 h = __float2bfloat16(f);
  return *reinterpret_cast<short*>(&h);
}

// ---------------- bf16 MFMA GEMM ----------------
// C[M,N] = A[M,K](bf16) @ Bw[N,K](bf16)^T, fp32 out. 128x128 tile, BK=32.
__global__ __launch_bounds__(256) void gemm_bf16_k(
    const short* __restrict__ A, const short* __restrict__ Bw,
    float* __restrict__ C, int M, int N, int K) {
  __shared__ short As[128 * 32];
  __shared__ short Bs[128 * 32];
  const int tid = threadIdx.x;
  const int wave = tid >> 6, lane = tid & 63;
  const int m0 = blockIdx.y * 128, n0 = blockIdx.x * 128;
  const int wm = (wave >> 1) * 64, wn = (wave & 1) * 64;
  const int fr = lane & 15, fk = (lane >> 4) * 8;

  f32x4 acc[4][4];
#pragma unroll
  for (int i = 0; i < 4; i++)
#pragma unroll
    for (int j = 0; j < 4; j++) acc[i][j] = (f32x4){0.f, 0.f, 0.f, 0.f};

  const int srow = tid >> 2, scol = (tid & 3) * 8;
  const short* gA = A + (size_t)(m0 + srow) * K + scol;
  const short* gB = Bw + (size_t)(n0 + srow) * K + scol;
  short* lA0 = &As[wave * 512];
  short* lA1 = &As[2048 + wave * 512];
  short* lB0 = &Bs[wave * 512];
  short* lB1 = &Bs[2048 + wave * 512];

  for (int k0 = 0; k0 < K; k0 += 32) {
    GLD16(gA + k0, lA0);
    GLD16(gA + (size_t)64 * K + k0, lA1);
    GLD16(gB + k0, lB0);
    GLD16(gB + (size_t)64 * K + k0, lB1);
    __syncthreads();

    bf16x8 af[4], bf[4];
#pragma unroll
    for (int i = 0; i < 4; i++)
      af[i] = *(const bf16x8*)&As[(wm + i * 16 + fr) * 32 + fk];
#pragma unroll
    for (int j = 0; j < 4; j++)
      bf[j] = *(const bf16x8*)&Bs[(wn + j * 16 + fr) * 32 + fk];
#pragma unroll
    for (int i = 0; i < 4; i++)
#pragma unroll
      for (int j = 0; j < 4; j++)
        acc[i][j] =
            __builtin_amdgcn_mfma_f32_16x16x32_bf16(af[i], bf[j], acc[i][j], 0, 0, 0);
    __syncthreads();
  }

  // C/D layout: col = lane&15, row = (lane>>4)*4 + reg  [m89/m91 verified]
#pragma unroll
  for (int i = 0; i < 4; i++) {
    const int gm = m0 + wm + i * 16 + (lane >> 4) * 4;
#pragma unroll
    for (int j = 0; j < 4; j++) {
      const int gn = n0 + wn + j * 16 + fr;
#pragma unroll
      for (int rix = 0; rix < 4; rix++)
        C[(size_t)(gm + rix) * N + gn] = acc[i][j][rix];
    }
  }
}

// ---------------- fp32 GEMM (small paths) ----------------
enum { EPI_NONE = 0, EPI_TANH, EPI_WDECAY, EPI_SIGBIAS, EPI_SIGMOID, EPI_VMIX };

template <bool MIX, bool BT, int EPI>
__global__ __launch_bounds__(256) void gemm_k(
    const float* __restrict__ A, const float* __restrict__ Bm,
    float* __restrict__ Cc, int M, int N, int K,
    const float* __restrict__ lam, const float* __restrict__ bias,
    const float* __restrict__ ex1, const float* __restrict__ ex2) {
  __shared__ float As[64][20];
  __shared__ float Bs[64][20];
  const int tid = threadIdx.x;
  const int n0 = blockIdx.x * 64;
  const int m0 = blockIdx.y * 64;
  const int tx = tid & 15, ty = tid >> 4;

  float acc[4][4];
#pragma unroll
  for (int i = 0; i < 4; i++)
#pragma unroll
    for (int j = 0; j < 4; j++) acc[i][j] = 0.f;

  const int lm = tid >> 2;
  const int lk4 = (tid & 3) * 4;

  for (int k0 = 0; k0 < K; k0 += 16) {
    {
      const int gm = m0 + lm;
      const float* ap = A + (size_t)gm * K + k0 + lk4;
      float4 xa = *(const float4*)ap;
      if (MIX) {
        float4 xp = make_float4(0.f, 0.f, 0.f, 0.f);
        if ((gm % T_) != 0) xp = *(const float4*)(ap - K);
        const float4 l4 = *(const float4*)(lam + k0 + lk4);
        xa.x += (xp.x - xa.x) * l4.x;
        xa.y += (xp.y - xa.y) * l4.y;
        xa.z += (xp.z - xa.z) * l4.z;
        xa.w += (xp.w - xa.w) * l4.w;
      }
      *(float4*)&As[lm][lk4] = xa;
    }
    if (BT) {
      const int gn = n0 + lm;
      const float4 bv = *(const float4*)(Bm + (size_t)gn * K + k0 + lk4);
      *(float4*)&Bs[lm][lk4] = bv;
    } else {
      const int kl = tid >> 4;
      const int nl = (tid & 15) * 4;
      const float4 bv = *(const float4*)(Bm + (size_t)(k0 + kl) * N + n0 + nl);
      Bs[nl + 0][kl] = bv.x;
      Bs[nl + 1][kl] = bv.y;
      Bs[nl + 2][kl] = bv.z;
      Bs[nl + 3][kl] = bv.w;
    }
    __syncthreads();

#pragma unroll
    for (int kb = 0; kb < 16; kb += 4) {
      float a4[4][4], b4[4][4];
#pragma unroll
      for (int i = 0; i < 4; i++) {
        const float4 t = *(const float4*)&As[ty * 4 + i][kb];
        a4[i][0] = t.x; a4[i][1] = t.y; a4[i][2] = t.z; a4[i][3] = t.w;
      }
#pragma unroll
      for (int j = 0; j < 4; j++) {
        const float4 t = *(const float4*)&Bs[tx * 4 + j][kb];
        b4[j][0] = t.x; b4[j][1] = t.y; b4[j][2] = t.z; b4[j][3] = t.w;
      }
#pragma unroll
      for (int u = 0; u < 4; u++)
#pragma unroll
        for (int i = 0; i < 4; i++)
#pragma unroll
          for (int j = 0; j < 4; j++)
            acc[i][j] = fmaf(a4[i][u], b4[j][u], acc[i][j]);
    }
    __syncthreads();
  }

#pragma unroll
  for (int i = 0; i < 4; i++) {
    const int gm = m0 + ty * 4 + i;
    float res[4];
#pragma unroll
    for (int j = 0; j < 4; j++) {
      const int n = n0 + tx * 4 + j;
      float val = acc[i][j];
      if (EPI == EPI_TANH) {
        val = tanhf(val);
      } else if (EPI == EPI_WDECAY) {
        const float u = bias[n] + val;
        const float sig = 1.f / (1.f + expf(-u));
        val = expf(-0.60653065971263342f * sig);
      } else if (EPI == EPI_SIGBIAS) {
        const float u = bias[n] + val;
        val = 1.f / (1.f + expf(-u));
      } else if (EPI == EPI_SIGMOID) {
        val = 1.f / (1.f + expf(-val));
      } else if (EPI == EPI_VMIX) {
        const float u = bias[n] + val;
        const float sg = 1.f / (1.f + expf(-u));
        const size_t off = (size_t)gm * N + n;
        const float v0v = ex1[off];
        const float vf = ex2[off];
        val = v0v + (vf - v0v) * sg;
      }
      res[j] = val;
    }
    *(float4*)(Cc + (size_t)gm * N + n0 + tx * 4) =
        make_float4(res[0], res[1], res[2], res[3]);
  }
}

// ---------------- mix -> bf16 (3 lambdas) ----------------
__global__ __launch_bounds__(256) void mix3_k(
    const float* __restrict__ x, const float* __restrict__ lr,
    const float* __restrict__ lk, const float* __restrict__ lv,
    short* __restrict__ xr, short* __restrict__ xk, short* __restrict__ xv) {
  const int i = blockIdx.x * 256 + threadIdx.x;  // float4 index
  const int c4 = i % (C_ / 4);
  const int gm = i / (C_ / 4);
  const float4 xa = ((const float4*)x)[i];
  float4 xp = make_float4(0.f, 0.f, 0.f, 0.f);
  if ((gm % T_) != 0) xp = ((const float4*)x)[i - C_ / 4];
  const float4 dx = make_float4(xp.x - xa.x, xp.y - xa.y, xp.z - xa.z, xp.w - xa.w);

  const float4 l1 = ((const float4*)lr)[c4];
  const float4 l2 = ((const float4*)lk)[c4];
  const float4 l3 = ((const float4*)lv)[c4];
  short4 o1 = {bf16b(fmaf(dx.x, l1.x, xa.x)), bf16b(fmaf(dx.y, l1.y, xa.y)),
               bf16b(fmaf(dx.z, l1.z, xa.z)), bf16b(fmaf(dx.w, l1.w, xa.w))};
  short4 o2 = {bf16b(fmaf(dx.x, l2.x, xa.x)), bf16b(fmaf(dx.y, l2.y, xa.y)),
               bf16b(fmaf(dx.z, l2.z, xa.z)), bf16b(fmaf(dx.w, l2.w, xa.w))};
  short4 o3 = {bf16b(fmaf(dx.x, l3.x, xa.x)), bf16b(fmaf(dx.y, l3.y, xa.y)),
               bf16b(fmaf(dx.z, l3.z, xa.z)), bf16b(fmaf(dx.w, l3.w, xa.w))};
  ((short4*)xr)[i] = o1;
  ((short4*)xk)[i] = o2;
  ((short4*)xv)[i] = o3;
}

// ---------------- fp32 -> bf16 convert, 4 weight mats in one launch ------
__global__ __launch_bounds__(256) void cvtw4_k(
    const float* __restrict__ w0, const float* __restrict__ w1,
    const float* __restrict__ w2, const float* __restrict__ w3,
    short* __restrict__ o0, short* __restrict__ o1s,
    short* __restrict__ o2s, short* __restrict__ o3s, int n4) {
  const int i = blockIdx.x * 256 + threadIdx.x;
  if (i >= n4) return;
  const float* src;
  short* dst;
  switch (blockIdx.y) {
    case 0: src = w0; dst = o0; break;
    case 1: src = w1; dst = o1s; break;
    case 2: src = w2; dst = o2s; break;
    default: src = w3; dst = o3s; break;
  }
  const float4 v = ((const float4*)src)[i];
  short4 o = {bf16b(v.x), bf16b(v.y), bf16b(v.z), bf16b(v.w)};
  ((short4*)dst)[i] = o;
}

// ---------------- kk prep ----------------
__global__ __launch_bounds__(256) void kkprep_k(
    const float* __restrict__ k0, const float* __restrict__ a,
    const float* __restrict__ k_k, const float* __restrict__ k_a,
    float* __restrict__ kout, float* __restrict__ z, float* __restrict__ bb) {
  const int wid = threadIdx.x >> 6;
  const int lane = threadIdx.x & 63;
  const size_t hid = (size_t)blockIdx.x * 4 + wid;
  const int h = (int)(hid % H_);
  const size_t idx = hid * 64 + lane;
  const int c = h * 64 + lane;
  const float kv = k0[idx];
  const float av = a[idx];
  const float kk = kv * k_k[c];
  const float ss = wave_sum64(kk * kk);
  const float denom = fmaxf(sqrtf(ss), 1e-12f);
  const float kkn = kk / denom;
  z[idx] = -kkn;
  bb[idx] = kkn * av;
  kout[idx] = kv * (1.f + (av - 1.f) * k_a[c]);
}

// ---------------- WKV-7 recurrence ----------------
// R6: 96 blocks x 256 threads (4 waves). Each 16-lane group owns TWO rows
// (rA, rA+16) of the 64x64 state; 4 cols/lane. The two rows share all
// column-stream data (w/z/b/k/r) -> 2x ILP at zero extra LDS traffic; the
// independent DPP reduction ladders hide each other's latency (1 wave/SIMD,
// no TLP available). Chunked LDS double-buffer staging as R5.
#define CH 16
#define NC (T_ / CH)
__global__ __launch_bounds__(256) void wkv7_k(
    const float* __restrict__ rr, const float* __restrict__ dd,
    const float* __restrict__ kk, const float* __restrict__ vv,
    const float* __restrict__ zz, const float* __restrict__ bbv,
    float* __restrict__ yy) {
  __shared__ float lds[2][6 * CH * 64];  // 2 x 24 KB
  const int blk = blockIdx.x;            // 0..95
  const int bh = blk % 48;               // 48 == 0 mod 8: same-head halves
  const int half = blk / 48;             // share an XCD under round-robin
  const int b = bh / H_, h = bh % H_;
  const int tid = threadIdx.x;
  const int wave = tid >> 6;
  const int l = tid & 63;
  const int l16 = l & 15;
  const int grp = l >> 4;
  const int rA = half * 32 + wave * 4 + grp;
  const int rB = rA + 16;
  const int cb = l16 * 4;
  const size_t btb = (size_t)b * T_;

  // staging: wave w covers timesteps [w*4, w*4+4) of the chunk for all 6
  // streams; lane l -> step (l>>4), cols (l&15)*4. LDS dest is linear.
  const size_t g0 = (btb + wave * 4 + grp) * C_ + h * 64 + cb;
  const int dbase = wave * 256;  // floats: 4 steps * 64

#define STAGE(BUF, GOFF)                                                      \
  {                                                                           \
    float* Ld = &lds[BUF][0];                                                 \
    GLD16(dd + (GOFF), Ld + 0 * 1024 + dbase);                                \
    GLD16(zz + (GOFF), Ld + 1 * 1024 + dbase);                                \
    GLD16(bbv + (GOFF), Ld + 2 * 1024 + dbase);                               \
    GLD16(kk + (GOFF), Ld + 3 * 1024 + dbase);                                \
    GLD16(rr + (GOFF), Ld + 4 * 1024 + dbase);                                \
    GLD16(vv + (GOFF), Ld + 5 * 1024 + dbase);                                \
  }

#define LDSTEP(S_, TL_)                                                       \
  {                                                                           \
    Wf[S_] = *(const float4*)&Lb[0 * 1024 + (TL_) * 64 + cb];                 \
    Zf[S_] = *(const float4*)&Lb[1 * 1024 + (TL_) * 64 + cb];                 \
    Bf[S_] = *(const float4*)&Lb[2 * 1024 + (TL_) * 64 + cb];                 \
    Kf[S_] = *(const float4*)&Lb[3 * 1024 + (TL_) * 64 + cb];                 \
    Rf[S_] = *(const float4*)&Lb[4 * 1024 + (TL_) * 64 + cb];                 \
    VfA[S_] = Lb[5 * 1024 + (TL_) * 64 + rA];                                 \
    VfB[S_] = Lb[5 * 1024 + (TL_) * 64 + rB];                                 \
  }

  STAGE(0, g0);
  __syncthreads();

  float SA0 = 0.f, SA1 = 0.f, SA2 = 0.f, SA3 = 0.f;
  float SB0 = 0.f, SB1 = 0.f, SB2 = 0.f, SB3 = 0.f;
  size_t gpf = g0 + (size_t)CH * C_;
  const size_t ybaseA = btb * C_ + h * 64 + rA;
  const size_t ybaseB = btb * C_ + h * 64 + rB;

  for (int c = 0; c < NC; ++c) {
    if (c + 1 < NC) STAGE((c + 1) & 1, gpf);
    gpf += (size_t)CH * C_;
    const float* Lb = lds[c & 1];

    float4 Wf[3], Zf[3], Bf[3], Kf[3], Rf[3];
    float VfA[3], VfB[3];
    LDSTEP(0, 0);
    LDSTEP(1, 1);
#pragma unroll
    for (int tl = 0; tl < CH; ++tl) {
      const int sl = tl % 3;  // compile-time after unroll
      if (tl + 2 < CH) {
        const int s2 = (tl + 2) % 3;
        LDSTEP(s2, tl + 2);
      }
      const float4 w4 = Wf[sl], z4 = Zf[sl], b4 = Bf[sl], k4 = Kf[sl],
                   r4 = Rf[sl];
      const float viA = VfA[sl], viB = VfB[sl];

      // two independent dot+reduce chains (rows rA, rB) interleave
      float saA = fmaf(SA1, z4.y, SA0 * z4.x) + fmaf(SA3, z4.w, SA2 * z4.z);
      float saB = fmaf(SB1, z4.y, SB0 * z4.x) + fmaf(SB3, z4.w, SB2 * z4.z);
      saA = row_sum16(saA);
      saB = row_sum16(saB);

      SA0 = fmaf(SA0, w4.x, fmaf(saA, b4.x, viA * k4.x));
      SA1 = fmaf(SA1, w4.y, fmaf(saA, b4.y, viA * k4.y));
      SA2 = fmaf(SA2, w4.z, fmaf(saA, b4.z, viA * k4.z));
      SA3 = fmaf(SA3, w4.w, fmaf(saA, b4.w, viA * k4.w));
      SB0 = fmaf(SB0, w4.x, fmaf(saB, b4.x, viB * k4.x));
      SB1 = fmaf(SB1, w4.y, fmaf(saB, b4.y, viB * k4.y));
      SB2 = fmaf(SB2, w4.z, fmaf(saB, b4.z, viB * k4.z));
      SB3 = fmaf(SB3, w4.w, fmaf(saB, b4.w, viB * k4.w));

      float ypA = fmaf(SA1, r4.y, SA0 * r4.x) + fmaf(SA3, r4.w, SA2 * r4.z);
      float ypB = fmaf(SB1, r4.y, SB0 * r4.x) + fmaf(SB3, r4.w, SB2 * r4.z);
      ypA = row_sum16(ypA);
      ypB = row_sum16(ypB);

      const size_t toff = (size_t)(c * CH + tl) * C_;
      if (l16 == 0)
        yy[ybaseA + toff] = ypA;
      else if (l16 == 1)
        yy[ybaseB + toff] = ypB;
    }
    __syncthreads();  // implicit vmcnt(0): staging for c+1 landed; all waves
                      // done reading buf c&1 before it is restaged
  }
#undef STAGE
#undef LDSTEP
}

// ---------------- GroupNorm + r_k term + g gating -> bf16 ----------------
__global__ __launch_bounds__(256) void gn_k(
    const float* __restrict__ y, const float* __restrict__ r,
    const float* __restrict__ k, const float* __restrict__ v,
    const float* __restrict__ g, const float* __restrict__ r_k,
    const float* __restrict__ ln_w, const float* __restrict__ ln_b,
    short* __restrict__ ymb) {
  const int wid = threadIdx.x >> 6;
  const int lane = threadIdx.x & 63;
  const size_t hid = (size_t)blockIdx.x * 4 + wid;
  const int h = (int)(hid % H_);
  const size_t idx = hid * 64 + lane;
  const int c = h * 64 + lane;

  const float yv = y[idx];
  const float mu = wave_sum64(yv) * (1.f / 64.f);
  const float sq = wave_sum64(yv * yv) * (1.f / 64.f);
  const float var = sq - mu * mu;
  float yn = (yv - mu) * rsqrtf(var + 0.00064f);
  yn = yn * ln_w[c] + ln_b[c];

  const float s = wave_sum64(r[idx] * k[idx] * r_k[c]);
  yn += s * v[idx];
  ymb[idx] = bf16b(yn * g[idx]);
}

// ---------------- copy ----------------
__global__ __launch_bounds__(256) void copy4_k(const float4* __restrict__ src,
                                               float4* __restrict__ dst, int n4) {
  const int i = blockIdx.x * blockDim.x + threadIdx.x;
  if (i < n4) dst[i] = src[i];
}

// ---------------- host launcher ----------------
template <bool MIX, bool BT, int EPI>
static void launch_gemm(const float* A, const float* Bm, float* Cc, int M,
                        int N, int K, const float* lam, const float* bias,
                        const float* ex1, const float* ex2, hipStream_t s) {
  dim3 grid(N / 64, M / 64), blk(256);
  hipLaunchKernelGGL((gemm_k<MIX, BT, EPI>), grid, blk, 0, s, A, Bm, Cc, M, N,
                     K, lam, bias, ex1, ex2);
}

extern "C" void kernel_launch(void* const* d_in, const int* in_sizes, int n_in,
                              void* d_out, int out_size, void* d_ws,
                              size_t ws_size, hipStream_t stream) {
  const float* x       = (const float*)d_in[0];
  const float* v_first = (const float*)d_in[1];
  const float* lam_r   = (const float*)d_in[2];
  const float* lam_w   = (const float*)d_in[3];
  const float* lam_k   = (const float*)d_in[4];
  const float* lam_v   = (const float*)d_in[5];
  const float* lam_a   = (const float*)d_in[6];
  const float* lam_g   = (const float*)d_in[7];
  const float* w_miu   = (const float*)d_in[8];
  const float* w_A     = (const float*)d_in[9];
  const float* w_B     = (const float*)d_in[10];
  const float* a_miu   = (const float*)d_in[11];
  const float* a_A     = (const float*)d_in[12];
  const float* a_B     = (const float*)d_in[13];
  const float* v_miu   = (const float*)d_in[14];
  const float* v_A     = (const float*)d_in[15];
  const float* v_B     = (const float*)d_in[16];
  const float* g_A     = (const float*)d_in[17];
  const float* g_B     = (const float*)d_in[18];
  const float* k_k     = (const float*)d_in[19];
  const float* k_a     = (const float*)d_in[20];
  const float* r_k     = (const float*)d_in[21];
  const float* W_r     = (const float*)d_in[22];
  const float* W_k     = (const float*)d_in[23];
  const float* W_v     = (const float*)d_in[24];
  const float* W_o     = (const float*)d_in[25];
  const float* ln_w    = (const float*)d_in[26];
  const float* ln_b    = (const float*)d_in[27];

  const int M = B_ * T_;            // 8192
  const size_t S = (size_t)M * C_;  // 6291456

  float* ws   = (float*)d_ws;
  float* r_   = ws + 0 * S;
  float* kbuf = ws + 1 * S;
  float* vbuf = ws + 2 * S;
  float* dec_ = ws + 3 * S;
  float* a_   = ws + 4 * S;
  float* g_   = ws + 5 * S;
  float* z_   = ws + 6 * S;
  float* bb_  = ws + 7 * S;
  float* h_   = ws + 8 * S;                       // M*128 floats
  short* wb   = (short*)(h_ + (size_t)M * 128);   // 4 bf16 weight copies
  float* out  = (float*)d_out;

  // bf16 aliases (dead fp32 slots at time of use)
  short* xr  = (short*)dec_;  // consumed before decay written
  short* xk  = (short*)a_;    // consumed before a written
  short* xv  = (short*)g_;    // consumed before g written
  short* ymb = (short*)z_;    // written after z consumed by wkv7
  const int WN = C_ * C_;     // 589824
  short* wrb = wb + 0 * (size_t)WN;
  short* wkb = wb + 1 * (size_t)WN;
  short* wvb = wb + 2 * (size_t)WN;
  short* wob = wb + 3 * (size_t)WN;

  // 1) weights -> bf16 (one launch, 4 mats)
  {
    dim3 blk(256), grid(WN / 4 / 256, 4);
    hipLaunchKernelGGL(cvtw4_k, grid, blk, 0, stream, W_r, W_k, W_v, W_o,
                       wrb, wkb, wvb, wob, WN / 4);
  }
  // 2) mixed x -> bf16 (r/k/v lambdas)
  {
    dim3 blk(256), grid((int)(S / 4 / 256));
    hipLaunchKernelGGL(mix3_k, grid, blk, 0, stream, x, lam_r, lam_k, lam_v,
                       xr, xk, xv);
  }
  // 3) big projections via MFMA
  {
    dim3 blk(256), grid(C_ / 128, M / 128);
    hipLaunchKernelGGL(gemm_bf16_k, grid, blk, 0, stream, xr, wrb, r_, M, C_, C_);
    hipLaunchKernelGGL(gemm_bf16_k, grid, blk, 0, stream, xk, wkb, kbuf, M, C_, C_);
    hipLaunchKernelGGL(gemm_bf16_k, grid, blk, 0, stream, xv, wvb, vbuf, M, C_, C_);
  }
  // 4) v low-rank residual gate
  launch_gemm<false, false, EPI_NONE>(vbuf, v_A, h_, M, 64, C_, nullptr, nullptr, nullptr, nullptr, stream);
  launch_gemm<false, false, EPI_VMIX>(h_, v_B, vbuf, M, C_, 64, nullptr, v_miu, vbuf, v_first, stream);
  // 5) decay / a / g paths (fp32, mix fused)
  launch_gemm<true, false, EPI_TANH>(x, w_A, h_, M, 64, C_, lam_w, nullptr, nullptr, nullptr, stream);
  launch_gemm<false, false, EPI_WDECAY>(h_, w_B, dec_, M, C_, 64, nullptr, w_miu, nullptr, nullptr, stream);
  launch_gemm<true, false, EPI_NONE>(x, a_A, h_, M, 64, C_, lam_a, nullptr, nullptr, nullptr, stream);
  launch_gemm<false, false, EPI_SIGBIAS>(h_, a_B, a_, M, C_, 64, nullptr, a_miu, nullptr, nullptr, stream);
  launch_gemm<true, false, EPI_SIGMOID>(x, g_A, h_, M, 128, C_, lam_g, nullptr, nullptr, nullptr, stream);
  launch_gemm<false, false, EPI_NONE>(h_, g_B, g_, M, C_, 128, nullptr, nullptr, nullptr, nullptr, stream);
  // 6) kk prep
  {
    dim3 grid((B_ * T_ * H_) / 4), blk(256);
    hipLaunchKernelGGL(kkprep_k, grid, blk, 0, stream, kbuf, a_, k_k, k_a,
                       kbuf, z_, bb_);
  }
  // 7) recurrence -> y (a_ slot)
  {
    dim3 grid(B_ * H_ * 2), blk(256);
    hipLaunchKernelGGL(wkv7_k, grid, blk, 0, stream, r_, dec_, kbuf, vbuf, z_,
                       bb_, a_);
  }
  // 8) groupnorm + rk-term + gate -> ymb (bf16, z_ slot)
  {
    dim3 grid((B_ * T_ * H_) / 4), blk(256);
    hipLaunchKernelGGL(gn_k, grid, blk, 0, stream, a_, r_, kbuf, vbuf, g_, r_k,
                       ln_w, ln_b, ymb);
  }
  // 9) output projection via MFMA
  {
    dim3 blk(256), grid(C_ / 128, M / 128);
    hipLaunchKernelGGL(gemm_bf16_k, grid, blk, 0, stream, ymb, wob, out, M, C_, C_);
  }
  // 10) v_first passthrough
  {
    const int n4 = (int)(S / 4);
    dim3 grid((n4 + 255) / 256), blk(256);
    hipLaunchKernelGGL(copy4_k, grid, blk, 0, stream, (const float4*)v_first,
                       (float4*)(out + S), n4);
  }
}

// Round 4
// 754.281 us; speedup vs baseline: 1.7891x; 1.7891x over previous
//
#include <hip/hip_runtime.h>
#include <hip/hip_bf16.h>
#include <math.h>

// RWKV-7 TimeMix. R7: revert wkv7 to R5 (proven 321us); move ALL eight
// fp32 small GEMMs to bf16 MFMA (stage-1 128x64-tile kernel with fused
// tanh/sigmoid epilogues -> bf16 h; stage-2 128x128 MFMA with fused
// WDECAY/SIGBIAS/VMIX epilogues); mix3 -> mix6 single pass.
// B=4 T=2048 C=768 H=12 N=64, LAYER_ID=1.

#define B_  4
#define T_  2048
#define C_  768
#define H_  12

typedef __attribute__((ext_vector_type(8))) short bf16x8;
typedef __attribute__((ext_vector_type(4))) float f32x4;

#define GLD16(gsrc, ldst)                                                     \
  __builtin_amdgcn_global_load_lds(                                           \
      (const __attribute__((address_space(1))) void*)(gsrc),                  \
      (__attribute__((address_space(3))) void*)(ldst), 16, 0, 0)

// ---- DPP helpers: sum across each 16-lane DPP row, all-VALU ----
template <int CTRL>
static __device__ __forceinline__ float row_ror_add(float v) {
  int t = __builtin_amdgcn_update_dpp(0, __float_as_int(v), CTRL, 0xF, 0xF, true);
  return v + __int_as_float(t);
}
static __device__ __forceinline__ float row_sum16(float v) {
  v = row_ror_add<0x128>(v);  // row_ror:8
  v = row_ror_add<0x124>(v);  // row_ror:4
  v = row_ror_add<0x122>(v);  // row_ror:2
  v = row_ror_add<0x121>(v);  // row_ror:1
  return v;                   // every lane in the 16-group holds the sum
}

static __device__ __forceinline__ float wave_sum64(float v) {
  v = row_sum16(v);
  v += __shfl_xor(v, 16);
  v += __shfl_xor(v, 32);
  return v;
}

static __device__ __forceinline__ short bf16b(float f) {
  __hip_bfloat16 h = __float2bfloat16(f);
  return *reinterpret_cast<short*>(&h);
}

enum { EPI_NONE = 0, EPI_TANH, EPI_WDECAY, EPI_SIGBIAS, EPI_SIGMOID, EPI_VMIX };

static __device__ __forceinline__ float apply_epi_f(int EPI, float val, int n,
                                                    int gmrow, int N,
                                                    const float* bias,
                                                    const float* ex1,
                                                    const float* ex2) {
  if (EPI == EPI_TANH) {
    val = tanhf(val);
  } else if (EPI == EPI_WDECAY) {
    const float u = bias[n] + val;
    const float sig = 1.f / (1.f + expf(-u));
    val = expf(-0.60653065971263342f * sig);
  } else if (EPI == EPI_SIGBIAS) {
    const float u = bias[n] + val;
    val = 1.f / (1.f + expf(-u));
  } else if (EPI == EPI_SIGMOID) {
    val = 1.f / (1.f + expf(-val));
  } else if (EPI == EPI_VMIX) {
    const float u = bias[n] + val;
    const float sg = 1.f / (1.f + expf(-u));
    const size_t off = (size_t)gmrow * N + n;
    const float v0v = ex1[off];
    const float vf = ex2[off];
    val = v0v + (vf - v0v) * sg;
  }
  return val;
}

// ---------------- bf16 MFMA GEMM, 128x128 tile, fused epilogue -----------
// C[M,N] = epi(A[M,K](bf16) @ Bw[N,K](bf16)^T), fp32 out (+optional bf16).
template <int EPI, bool DUAL>
__global__ __launch_bounds__(256) void gemm_epi_k(
    const short* __restrict__ A, const short* __restrict__ Bw,
    float* __restrict__ C, short* __restrict__ C16, int M, int N, int K,
    const float* __restrict__ bias, const float* __restrict__ ex1,
    const float* __restrict__ ex2) {
  __shared__ short As[128 * 32];
  __shared__ short Bs[128 * 32];
  const int tid = threadIdx.x;
  const int wave = tid >> 6, lane = tid & 63;
  const int m0 = blockIdx.y * 128, n0 = blockIdx.x * 128;
  const int wm = (wave >> 1) * 64, wn = (wave & 1) * 64;
  const int fr = lane & 15, fk = (lane >> 4) * 8;

  f32x4 acc[4][4];
#pragma unroll
  for (int i = 0; i < 4; i++)
#pragma unroll
    for (int j = 0; j < 4; j++) acc[i][j] = (f32x4){0.f, 0.f, 0.f, 0.f};

  const int srow = tid >> 2, scol = (tid & 3) * 8;
  const short* gA = A + (size_t)(m0 + srow) * K + scol;
  const short* gB = Bw + (size_t)(n0 + srow) * K + scol;
  short* lA0 = &As[wave * 512];
  short* lA1 = &As[2048 + wave * 512];
  short* lB0 = &Bs[wave * 512];
  short* lB1 = &Bs[2048 + wave * 512];

  for (int k0 = 0; k0 < K; k0 += 32) {
    GLD16(gA + k0, lA0);
    GLD16(gA + (size_t)64 * K + k0, lA1);
    GLD16(gB + k0, lB0);
    GLD16(gB + (size_t)64 * K + k0, lB1);
    __syncthreads();

    bf16x8 af[4], bf[4];
#pragma unroll
    for (int i = 0; i < 4; i++)
      af[i] = *(const bf16x8*)&As[(wm + i * 16 + fr) * 32 + fk];
#pragma unroll
    for (int j = 0; j < 4; j++)
      bf[j] = *(const bf16x8*)&Bs[(wn + j * 16 + fr) * 32 + fk];
#pragma unroll
    for (int i = 0; i < 4; i++)
#pragma unroll
      for (int j = 0; j < 4; j++)
        acc[i][j] =
            __builtin_amdgcn_mfma_f32_16x16x32_bf16(af[i], bf[j], acc[i][j], 0, 0, 0);
    __syncthreads();
  }

  // C/D layout: col = lane&15, row = (lane>>4)*4 + reg  [m89/m91 verified]
#pragma unroll
  for (int i = 0; i < 4; i++) {
    const int gm = m0 + wm + i * 16 + (lane >> 4) * 4;
#pragma unroll
    for (int j = 0; j < 4; j++) {
      const int gn = n0 + wn + j * 16 + fr;
#pragma unroll
      for (int rix = 0; rix < 4; rix++) {
        float val = acc[i][j][rix];
        val = apply_epi_f(EPI, val, gn, gm + rix, N, bias, ex1, ex2);
        C[(size_t)(gm + rix) * N + gn] = val;
        if (DUAL) C16[(size_t)(gm + rix) * N + gn] = bf16b(val);
      }
    }
  }
}

// ---------------- bf16 MFMA GEMM, 128x64 tile, bf16 out (stage-1) --------
// out16[M,N] = epi(A[M,K] @ Bw[N,K]^T), N is the full row stride.
template <int EPI>
__global__ __launch_bounds__(256) void gemm_s1_k(
    const short* __restrict__ A, const short* __restrict__ Bw,
    short* __restrict__ out16, int M, int N, int K) {
  __shared__ short As[128 * 32];
  __shared__ short Bs[64 * 32];
  const int tid = threadIdx.x;
  const int wave = tid >> 6, lane = tid & 63;
  const int m0 = blockIdx.y * 128, n0 = blockIdx.x * 64;
  const int wm = (wave >> 1) * 64, wn = (wave & 1) * 32;
  const int fr = lane & 15, fk = (lane >> 4) * 8;

  f32x4 acc[4][2];
#pragma unroll
  for (int i = 0; i < 4; i++)
#pragma unroll
    for (int j = 0; j < 2; j++) acc[i][j] = (f32x4){0.f, 0.f, 0.f, 0.f};

  const int srow = tid >> 2, scol = (tid & 3) * 8;
  const short* gA = A + (size_t)(m0 + srow) * K + scol;
  const short* gB = Bw + (size_t)(n0 + srow) * K + scol;  // srow<64 rows used
  short* lA0 = &As[wave * 512];
  short* lA1 = &As[2048 + wave * 512];
  short* lB0 = &Bs[wave * 512];

  for (int k0 = 0; k0 < K; k0 += 32) {
    GLD16(gA + k0, lA0);
    GLD16(gA + (size_t)64 * K + k0, lA1);
    GLD16(gB + k0, lB0);
    __syncthreads();

    bf16x8 af[4], bf[2];
#pragma unroll
    for (int i = 0; i < 4; i++)
      af[i] = *(const bf16x8*)&As[(wm + i * 16 + fr) * 32 + fk];
#pragma unroll
    for (int j = 0; j < 2; j++)
      bf[j] = *(const bf16x8*)&Bs[(wn + j * 16 + fr) * 32 + fk];
#pragma unroll
    for (int i = 0; i < 4; i++)
#pragma unroll
      for (int j = 0; j < 2; j++)
        acc[i][j] =
            __builtin_amdgcn_mfma_f32_16x16x32_bf16(af[i], bf[j], acc[i][j], 0, 0, 0);
    __syncthreads();
  }

#pragma unroll
  for (int i = 0; i < 4; i++) {
    const int gm = m0 + wm + i * 16 + (lane >> 4) * 4;
#pragma unroll
    for (int j = 0; j < 2; j++) {
      const int gn = n0 + wn + j * 16 + fr;
#pragma unroll
      for (int rix = 0; rix < 4; rix++) {
        float val = acc[i][j][rix];
        if (EPI == EPI_TANH) val = tanhf(val);
        else if (EPI == EPI_SIGMOID) val = 1.f / (1.f + expf(-val));
        out16[(size_t)(gm + rix) * N + gn] = bf16b(val);
      }
    }
  }
}

// ---------------- mix -> bf16 (6 lambdas, one pass) ----------------
__global__ __launch_bounds__(256) void mix6_k(
    const float* __restrict__ x, const float* __restrict__ lr,
    const float* __restrict__ lk, const float* __restrict__ lv,
    const float* __restrict__ lw, const float* __restrict__ la,
    const float* __restrict__ lg, short* __restrict__ xr,
    short* __restrict__ xk, short* __restrict__ xv, short* __restrict__ xw,
    short* __restrict__ xa, short* __restrict__ xg) {
  const int i = blockIdx.x * 256 + threadIdx.x;  // float4 index
  const int c4 = i % (C_ / 4);
  const int gm = i / (C_ / 4);
  const float4 xa4 = ((const float4*)x)[i];
  float4 xp = make_float4(0.f, 0.f, 0.f, 0.f);
  if ((gm % T_) != 0) xp = ((const float4*)x)[i - C_ / 4];
  const float4 dx =
      make_float4(xp.x - xa4.x, xp.y - xa4.y, xp.z - xa4.z, xp.w - xa4.w);

#define MIXOUT(dst, lam)                                                      \
  {                                                                           \
    const float4 l4 = ((const float4*)lam)[c4];                               \
    short4 o = {bf16b(fmaf(dx.x, l4.x, xa4.x)),                               \
                bf16b(fmaf(dx.y, l4.y, xa4.y)),                               \
                bf16b(fmaf(dx.z, l4.z, xa4.z)),                               \
                bf16b(fmaf(dx.w, l4.w, xa4.w))};                              \
    ((short4*)dst)[i] = o;                                                    \
  }
  MIXOUT(xr, lr);
  MIXOUT(xk, lk);
  MIXOUT(xv, lv);
  MIXOUT(xw, lw);
  MIXOUT(xa, la);
  MIXOUT(xg, lg);
#undef MIXOUT
}

// ---------------- fp32 -> bf16 convert, 4 weight mats in one launch ------
__global__ __launch_bounds__(256) void cvtw4_k(
    const float* __restrict__ w0, const float* __restrict__ w1,
    const float* __restrict__ w2, const float* __restrict__ w3,
    short* __restrict__ o0, short* __restrict__ o1s,
    short* __restrict__ o2s, short* __restrict__ o3s, int n4) {
  const int i = blockIdx.x * 256 + threadIdx.x;
  if (i >= n4) return;
  const float* src;
  short* dst;
  switch (blockIdx.y) {
    case 0: src = w0; dst = o0; break;
    case 1: src = w1; dst = o1s; break;
    case 2: src = w2; dst = o2s; break;
    default: src = w3; dst = o3s; break;
  }
  const float4 v = ((const float4*)src)[i];
  short4 o = {bf16b(v.x), bf16b(v.y), bf16b(v.z), bf16b(v.w)};
  ((short4*)dst)[i] = o;
}

// ------- transpose+convert fp32 [R,Cc] -> bf16 [Cc,R], 8 mats ------------
__global__ __launch_bounds__(256) void cvtT8_k(
    const float* __restrict__ i0, const float* __restrict__ i1,
    const float* __restrict__ i2, const float* __restrict__ i3,
    const float* __restrict__ i4, const float* __restrict__ i5,
    const float* __restrict__ i6, const float* __restrict__ i7,
    short* __restrict__ o0, short* __restrict__ o1,
    short* __restrict__ o2, short* __restrict__ o3,
    short* __restrict__ o4, short* __restrict__ o5,
    short* __restrict__ o6, short* __restrict__ o7) {
  const float* in;
  short* out;
  int R, Cc;
  switch (blockIdx.y) {
    case 0: in = i0; out = o0; R = C_; Cc = 64; break;   // w_A
    case 1: in = i1; out = o1; R = C_; Cc = 64; break;   // a_A
    case 2: in = i2; out = o2; R = C_; Cc = 64; break;   // v_A
    case 3: in = i3; out = o3; R = C_; Cc = 128; break;  // g_A
    case 4: in = i4; out = o4; R = 64; Cc = C_; break;   // w_B
    case 5: in = i5; out = o5; R = 64; Cc = C_; break;   // a_B
    case 6: in = i6; out = o6; R = 64; Cc = C_; break;   // v_B
    default: in = i7; out = o7; R = 128; Cc = C_; break; // g_B
  }
  const int n = R * Cc;
  for (int i = blockIdx.x * 256 + threadIdx.x; i < n; i += gridDim.x * 256) {
    const int r = i / Cc, c = i % Cc;
    out[(size_t)c * R + r] = bf16b(in[i]);
  }
}

// ---------------- kk prep ----------------
__global__ __launch_bounds__(256) void kkprep_k(
    const float* __restrict__ k0, const float* __restrict__ a,
    const float* __restrict__ k_k, const float* __restrict__ k_a,
    float* __restrict__ kout, float* __restrict__ z, float* __restrict__ bb) {
  const int wid = threadIdx.x >> 6;
  const int lane = threadIdx.x & 63;
  const size_t hid = (size_t)blockIdx.x * 4 + wid;
  const int h = (int)(hid % H_);
  const size_t idx = hid * 64 + lane;
  const int c = h * 64 + lane;
  const float kv = k0[idx];
  const float av = a[idx];
  const float kk = kv * k_k[c];
  const float ss = wave_sum64(kk * kk);
  const float denom = fmaxf(sqrtf(ss), 1e-12f);
  const float kkn = kk / denom;
  z[idx] = -kkn;
  bb[idx] = kkn * av;
  kout[idx] = kv * (1.f + (av - 1.f) * k_a[c]);
}

// ---------------- WKV-7 recurrence (R5 structure, proven 321us) ----------
// 192 blocks x 256 threads (4 waves). Chunked LDS double-buffer staging via
// global_load_lds; 2-step-ahead register ping-pong from LDS; DPP reductions.
#define CH 16
#define NC (T_ / CH)
__global__ __launch_bounds__(256) void wkv7_k(
    const float* __restrict__ rr, const float* __restrict__ dd,
    const float* __restrict__ kk, const float* __restrict__ vv,
    const float* __restrict__ zz, const float* __restrict__ bbv,
    float* __restrict__ yy) {
  __shared__ float lds[2][6 * CH * 64];  // 2 x 24 KB
  const int blk = blockIdx.x;
  const int bh = blk % 48;
  const int rq = blk / 48;
  const int b = bh / H_, h = bh % H_;
  const int tid = threadIdx.x;
  const int wave = tid >> 6;
  const int l = tid & 63;
  const int l16 = l & 15;
  const int row = rq * 16 + wave * 4 + (l >> 4);
  const int cb = l16 * 4;
  const size_t btb = (size_t)b * T_;

  const size_t g0 = (btb + wave * 4 + (l >> 4)) * C_ + h * 64 + cb;
  const int dbase = wave * 256;  // floats: 4 steps * 64

#define STAGE(BUF, GOFF)                                                      \
  {                                                                           \
    float* Ld = &lds[BUF][0];                                                 \
    GLD16(dd + (GOFF), Ld + 0 * 1024 + dbase);                                \
    GLD16(zz + (GOFF), Ld + 1 * 1024 + dbase);                                \
    GLD16(bbv + (GOFF), Ld + 2 * 1024 + dbase);                               \
    GLD16(kk + (GOFF), Ld + 3 * 1024 + dbase);                                \
    GLD16(rr + (GOFF), Ld + 4 * 1024 + dbase);                                \
    GLD16(vv + (GOFF), Ld + 5 * 1024 + dbase);                                \
  }

#define LDSTEP(S_, TL_)                                                       \
  {                                                                           \
    Wf[S_] = *(const float4*)&Lb[0 * 1024 + (TL_) * 64 + cb];                 \
    Zf[S_] = *(const float4*)&Lb[1 * 1024 + (TL_) * 64 + cb];                 \
    Bf[S_] = *(const float4*)&Lb[2 * 1024 + (TL_) * 64 + cb];                 \
    Kf[S_] = *(const float4*)&Lb[3 * 1024 + (TL_) * 64 + cb];                 \
    Rf[S_] = *(const float4*)&Lb[4 * 1024 + (TL_) * 64 + cb];                 \
    Vf[S_] = Lb[5 * 1024 + (TL_) * 64 + row];                                 \
  }

  STAGE(0, g0);
  __syncthreads();

  float S0 = 0.f, S1 = 0.f, S2 = 0.f, S3 = 0.f;
  size_t gpf = g0 + (size_t)CH * C_;
  const size_t ybase = btb * C_ + h * 64 + row;

  for (int c = 0; c < NC; ++c) {
    if (c + 1 < NC) STAGE((c + 1) & 1, gpf);
    gpf += (size_t)CH * C_;
    const float* Lb = lds[c & 1];

    float4 Wf[3], Zf[3], Bf[3], Kf[3], Rf[3];
    float Vf[3];
    LDSTEP(0, 0);
    LDSTEP(1, 1);
#pragma unroll
    for (int tl = 0; tl < CH; ++tl) {
      const int sl = tl % 3;  // compile-time after unroll
      if (tl + 2 < CH) {
        const int s2 = (tl + 2) % 3;
        LDSTEP(s2, tl + 2);
      }
      const float4 w4 = Wf[sl], z4 = Zf[sl], b4 = Bf[sl], k4 = Kf[sl],
                   r4 = Rf[sl];
      const float vi = Vf[sl];

      float sa = fmaf(S1, z4.y, S0 * z4.x) + fmaf(S3, z4.w, S2 * z4.z);
      sa = row_sum16(sa);

      S0 = fmaf(S0, w4.x, fmaf(sa, b4.x, vi * k4.x));
      S1 = fmaf(S1, w4.y, fmaf(sa, b4.y, vi * k4.y));
      S2 = fmaf(S2, w4.z, fmaf(sa, b4.z, vi * k4.z));
      S3 = fmaf(S3, w4.w, fmaf(sa, b4.w, vi * k4.w));

      float yp = fmaf(S1, r4.y, S0 * r4.x) + fmaf(S3, r4.w, S2 * r4.z);
      yp = row_sum16(yp);
      if (l16 == 0) yy[ybase + (size_t)(c * CH + tl) * C_] = yp;
    }
    __syncthreads();
  }
#undef STAGE
#undef LDSTEP
}

// ---------------- GroupNorm + r_k term + g gating -> bf16 ----------------
__global__ __launch_bounds__(256) void gn_k(
    const float* __restrict__ y, const float* __restrict__ r,
    const float* __restrict__ k, const float* __restrict__ v,
    const float* __restrict__ g, const float* __restrict__ r_k,
    const float* __restrict__ ln_w, const float* __restrict__ ln_b,
    short* __restrict__ ymb) {
  const int wid = threadIdx.x >> 6;
  const int lane = threadIdx.x & 63;
  const size_t hid = (size_t)blockIdx.x * 4 + wid;
  const int h = (int)(hid % H_);
  const size_t idx = hid * 64 + lane;
  const int c = h * 64 + lane;

  const float yv = y[idx];
  const float mu = wave_sum64(yv) * (1.f / 64.f);
  const float sq = wave_sum64(yv * yv) * (1.f / 64.f);
  const float var = sq - mu * mu;
  float yn = (yv - mu) * rsqrtf(var + 0.00064f);
  yn = yn * ln_w[c] + ln_b[c];

  const float s = wave_sum64(r[idx] * k[idx] * r_k[c]);
  yn += s * v[idx];
  ymb[idx] = bf16b(yn * g[idx]);
}

// ---------------- copy ----------------
__global__ __launch_bounds__(256) void copy4_k(const float4* __restrict__ src,
                                               float4* __restrict__ dst, int n4) {
  const int i = blockIdx.x * blockDim.x + threadIdx.x;
  if (i < n4) dst[i] = src[i];
}

// ---------------- host launcher ----------------
extern "C" void kernel_launch(void* const* d_in, const int* in_sizes, int n_in,
                              void* d_out, int out_size, void* d_ws,
                              size_t ws_size, hipStream_t stream) {
  const float* x       = (const float*)d_in[0];
  const float* v_first = (const float*)d_in[1];
  const float* lam_r   = (const float*)d_in[2];
  const float* lam_w   = (const float*)d_in[3];
  const float* lam_k   = (const float*)d_in[4];
  const float* lam_v   = (const float*)d_in[5];
  const float* lam_a   = (const float*)d_in[6];
  const float* lam_g   = (const float*)d_in[7];
  const float* w_miu   = (const float*)d_in[8];
  const float* w_A     = (const float*)d_in[9];
  const float* w_B     = (const float*)d_in[10];
  const float* a_miu   = (const float*)d_in[11];
  const float* a_A     = (const float*)d_in[12];
  const float* a_B     = (const float*)d_in[13];
  const float* v_miu   = (const float*)d_in[14];
  const float* v_A     = (const float*)d_in[15];
  const float* v_B     = (const float*)d_in[16];
  const float* g_A     = (const float*)d_in[17];
  const float* g_B     = (const float*)d_in[18];
  const float* k_k     = (const float*)d_in[19];
  const float* k_a     = (const float*)d_in[20];
  const float* r_k     = (const float*)d_in[21];
  const float* W_r     = (const float*)d_in[22];
  const float* W_k     = (const float*)d_in[23];
  const float* W_v     = (const float*)d_in[24];
  const float* W_o     = (const float*)d_in[25];
  const float* ln_w    = (const float*)d_in[26];
  const float* ln_b    = (const float*)d_in[27];

  const int M = B_ * T_;            // 8192
  const size_t S = (size_t)M * C_;  // 6291456

  float* ws   = (float*)d_ws;
  float* r_   = ws + 0 * S;
  float* kbuf = ws + 1 * S;
  float* vbuf = ws + 2 * S;
  float* dec_ = ws + 3 * S;
  float* a_   = ws + 4 * S;
  float* g_   = ws + 5 * S;
  float* z_   = ws + 6 * S;
  float* bb_  = ws + 7 * S;
  float* h_   = ws + 8 * S;                       // M*128 floats (stage-1 hs)
  short* wb   = (short*)(h_ + (size_t)M * 128);   // 4 bf16 weight copies
  float* out  = (float*)d_out;

  const int WN = C_ * C_;  // 589824
  short* wrb = wb + 0 * (size_t)WN;
  short* wkb = wb + 1 * (size_t)WN;
  short* wvb = wb + 2 * (size_t)WN;
  short* wob = wb + 3 * (size_t)WN;
  // transposed small weights (bf16), appended after big weights (~1 MB)
  short* wAT = wb + 4 * (size_t)WN;
  short* aAT = wAT + (size_t)C_ * 64;
  short* vAT = aAT + (size_t)C_ * 64;
  short* gAT = vAT + (size_t)C_ * 64;
  short* wBT = gAT + (size_t)C_ * 128;
  short* aBT = wBT + (size_t)C_ * 64;
  short* vBT = aBT + (size_t)C_ * 64;
  short* gBT = vBT + (size_t)C_ * 64;

  // bf16 aliases in dead fp32 slots (each mix buffer = S shorts = half slot)
  short* xr  = (short*)dec_;            // consumed before dec_ written
  short* xk  = (short*)a_;              // consumed before a_ written
  short* xv  = (short*)g_;              // consumed before g_ written
  short* xw  = (short*)z_;              // consumed before kkprep writes z_
  short* xa  = (short*)z_ + S;          // second half of z_ slot
  short* xg  = (short*)bb_;             // consumed before kkprep writes bb_
  short* vbuf16 = (short*)bb_ + S;      // second half of bb_ slot
  short* h_w = (short*)h_;              // M*64
  short* h_a = h_w + (size_t)M * 64;    // M*64
  short* h_g = h_a + (size_t)M * 64;    // M*128
  short* h_v = (short*)dec_ + S;        // second half of dec_ slot;
                                        // consumed by S2-v BEFORE S2-w writes dec_
  short* ymb = (short*)z_;              // written after wkv7 consumed z_

  // 1) big weights -> bf16 (one launch, 4 mats)
  {
    dim3 blk(256), grid(WN / 4 / 256, 4);
    hipLaunchKernelGGL(cvtw4_k, grid, blk, 0, stream, W_r, W_k, W_v, W_o,
                       wrb, wkb, wvb, wob, WN / 4);
  }
  // 2) small weights -> transposed bf16 (one launch, 8 mats)
  {
    dim3 blk(256), grid((C_ * 128 + 255) / 256, 8);
    hipLaunchKernelGGL(cvtT8_k, grid, blk, 0, stream, w_A, a_A, v_A, g_A,
                       w_B, a_B, v_B, g_B, wAT, aAT, vAT, gAT, wBT, aBT, vBT,
                       gBT);
  }
  // 3) mixed x -> bf16, all 6 lambdas in one pass
  {
    dim3 blk(256), grid((int)(S / 4 / 256));
    hipLaunchKernelGGL(mix6_k, grid, blk, 0, stream, x, lam_r, lam_k, lam_v,
                       lam_w, lam_a, lam_g, xr, xk, xv, xw, xa, xg);
  }
  // 4) big projections via MFMA (v also emits bf16 copy for S1-v)
  {
    dim3 blk(256), grid(C_ / 128, M / 128);
    hipLaunchKernelGGL((gemm_epi_k<EPI_NONE, false>), grid, blk, 0, stream,
                       xr, wrb, r_, (short*)nullptr, M, C_, C_, nullptr,
                       nullptr, nullptr);
    hipLaunchKernelGGL((gemm_epi_k<EPI_NONE, false>), grid, blk, 0, stream,
                       xk, wkb, kbuf, (short*)nullptr, M, C_, C_, nullptr,
                       nullptr, nullptr);
    hipLaunchKernelGGL((gemm_epi_k<EPI_NONE, true>), grid, blk, 0, stream,
                       xv, wvb, vbuf, vbuf16, M, C_, C_, nullptr, nullptr,
                       nullptr);
  }
  // 5) stage-1 low-rank projections (bf16 MFMA, fused activations)
  {
    dim3 blk(256);
    dim3 g64(1, M / 128), g128(2, M / 128);
    hipLaunchKernelGGL((gemm_s1_k<EPI_TANH>), g64, blk, 0, stream, xw, wAT,
                       h_w, M, 64, C_);
    hipLaunchKernelGGL((gemm_s1_k<EPI_NONE>), g64, blk, 0, stream, xa, aAT,
                       h_a, M, 64, C_);
    hipLaunchKernelGGL((gemm_s1_k<EPI_SIGMOID>), g128, blk, 0, stream, xg,
                       gAT, h_g, M, 128, C_);
    hipLaunchKernelGGL((gemm_s1_k<EPI_NONE>), g64, blk, 0, stream, vbuf16,
                       vAT, h_v, M, 64, C_);
  }
  // 6) stage-2 expansions (bf16 MFMA, fused epilogues). Order matters:
  //    S2-v must consume h_v before S2-w clobbers dec_'s second half.
  {
    dim3 blk(256), grid(C_ / 128, M / 128);
    hipLaunchKernelGGL((gemm_epi_k<EPI_VMIX, false>), grid, blk, 0, stream,
                       h_v, vBT, vbuf, (short*)nullptr, M, C_, 64, v_miu,
                       vbuf, v_first);
    hipLaunchKernelGGL((gemm_epi_k<EPI_WDECAY, false>), grid, blk, 0, stream,
                       h_w, wBT, dec_, (short*)nullptr, M, C_, 64, w_miu,
                       nullptr, nullptr);
    hipLaunchKernelGGL((gemm_epi_k<EPI_SIGBIAS, false>), grid, blk, 0, stream,
                       h_a, aBT, a_, (short*)nullptr, M, C_, 64, a_miu,
                       nullptr, nullptr);
    hipLaunchKernelGGL((gemm_epi_k<EPI_NONE, false>), grid, blk, 0, stream,
                       h_g, gBT, g_, (short*)nullptr, M, C_, 128, nullptr,
                       nullptr, nullptr);
  }
  // 7) kk prep
  {
    dim3 grid((B_ * T_ * H_) / 4), blk(256);
    hipLaunchKernelGGL(kkprep_k, grid, blk, 0, stream, kbuf, a_, k_k, k_a,
                       kbuf, z_, bb_);
  }
  // 8) recurrence -> y (a_ slot)
  {
    dim3 grid(B_ * H_ * 4), blk(256);
    hipLaunchKernelGGL(wkv7_k, grid, blk, 0, stream, r_, dec_, kbuf, vbuf, z_,
                       bb_, a_);
  }
  // 9) groupnorm + rk-term + gate -> ymb (bf16, z_ slot)
  {
    dim3 grid((B_ * T_ * H_) / 4), blk(256);
    hipLaunchKernelGGL(gn_k, grid, blk, 0, stream, a_, r_, kbuf, vbuf, g_, r_k,
                       ln_w, ln_b, ymb);
  }
  // 10) output projection via MFMA
  {
    dim3 blk(256), grid(C_ / 128, M / 128);
    hipLaunchKernelGGL((gemm_epi_k<EPI_NONE, false>), grid, blk, 0, stream,
                       ymb, wob, out, (short*)nullptr, M, C_, C_, nullptr,
                       nullptr, nullptr);
  }
  // 11) v_first passthrough
  {
    const int n4 = (int)(S / 4);
    dim3 grid((n4 + 255) / 256), blk(256);
    hipLaunchKernelGGL(copy4_k, grid, blk, 0, stream, (const float4*)v_first,
                       (float4*)(out + S), n4);
  }
}

// Round 5
// 738.427 us; speedup vs baseline: 1.8275x; 1.0215x over previous
//
#include <hip/hip_runtime.h>
#include <hip/hip_bf16.h>
#include <math.h>

// RWKV-7 TimeMix. R8: (1) wkv7 v-stream moved from LDS to chunk-ahead global
// register prefetch (5 staged streams, 40KB LDS); (2) stage-2-g GEMM + v_first
// copy fused into the wkv7 launch as role-blocks on idle CUs; (3) launches
// merged 21 -> 9 (big3 / s1x4 / s2x3 / wprep12).
// B=4 T=2048 C=768 H=12 N=64, LAYER_ID=1.

#define B_  4
#define T_  2048
#define C_  768
#define H_  12

typedef __attribute__((ext_vector_type(8))) short bf16x8;
typedef __attribute__((ext_vector_type(4))) float f32x4;

#define GLD16(gsrc, ldst)                                                     \
  __builtin_amdgcn_global_load_lds(                                           \
      (const __attribute__((address_space(1))) void*)(gsrc),                  \
      (__attribute__((address_space(3))) void*)(ldst), 16, 0, 0)

// ---- DPP helpers: sum across each 16-lane DPP row, all-VALU ----
template <int CTRL>
static __device__ __forceinline__ float row_ror_add(float v) {
  int t = __builtin_amdgcn_update_dpp(0, __float_as_int(v), CTRL, 0xF, 0xF, true);
  return v + __int_as_float(t);
}
static __device__ __forceinline__ float row_sum16(float v) {
  v = row_ror_add<0x128>(v);  // row_ror:8
  v = row_ror_add<0x124>(v);  // row_ror:4
  v = row_ror_add<0x122>(v);  // row_ror:2
  v = row_ror_add<0x121>(v);  // row_ror:1
  return v;
}

static __device__ __forceinline__ float wave_sum64(float v) {
  v = row_sum16(v);
  v += __shfl_xor(v, 16);
  v += __shfl_xor(v, 32);
  return v;
}

static __device__ __forceinline__ short bf16b(float f) {
  __hip_bfloat16 h = __float2bfloat16(f);
  return *reinterpret_cast<short*>(&h);
}

enum { EPI_NONE = 0, EPI_TANH, EPI_WDECAY, EPI_SIGBIAS, EPI_SIGMOID, EPI_VMIX };

static __device__ __forceinline__ float apply_epi_f(int epi, float val, int n,
                                                    int gmrow, int N,
                                                    const float* bias,
                                                    const float* ex1,
                                                    const float* ex2) {
  if (epi == EPI_TANH) {
    val = tanhf(val);
  } else if (epi == EPI_WDECAY) {
    const float u = bias[n] + val;
    const float sig = 1.f / (1.f + expf(-u));
    val = expf(-0.60653065971263342f * sig);
  } else if (epi == EPI_SIGBIAS) {
    const float u = bias[n] + val;
    val = 1.f / (1.f + expf(-u));
  } else if (epi == EPI_SIGMOID) {
    val = 1.f / (1.f + expf(-val));
  } else if (epi == EPI_VMIX) {
    const float u = bias[n] + val;
    const float sg = 1.f / (1.f + expf(-u));
    const size_t off = (size_t)gmrow * N + n;
    const float v0v = ex1[off];
    const float vf = ex2[off];
    val = v0v + (vf - v0v) * sg;
  }
  return val;
}

// ---------------- bf16 MFMA GEMM tile bodies (device functions) ----------
// 128x128 tile, BK=32, fp32 out (+optional bf16 dual).
static __device__ __forceinline__ void gemm128_tile(
    const short* __restrict__ A, const short* __restrict__ Bw,
    float* __restrict__ C, short* __restrict__ C16, int M, int N, int K,
    int bx, int by, int epi, const float* bias, const float* ex1,
    const float* ex2, short* As, short* Bs) {
  const int tid = threadIdx.x;
  const int wave = tid >> 6, lane = tid & 63;
  const int m0 = by * 128, n0 = bx * 128;
  const int wm = (wave >> 1) * 64, wn = (wave & 1) * 64;
  const int fr = lane & 15, fk = (lane >> 4) * 8;

  f32x4 acc[4][4];
#pragma unroll
  for (int i = 0; i < 4; i++)
#pragma unroll
    for (int j = 0; j < 4; j++) acc[i][j] = (f32x4){0.f, 0.f, 0.f, 0.f};

  const int srow = tid >> 2, scol = (tid & 3) * 8;
  const short* gA = A + (size_t)(m0 + srow) * K + scol;
  const short* gB = Bw + (size_t)(n0 + srow) * K + scol;
  short* lA0 = &As[wave * 512];
  short* lA1 = &As[2048 + wave * 512];
  short* lB0 = &Bs[wave * 512];
  short* lB1 = &Bs[2048 + wave * 512];

  for (int k0 = 0; k0 < K; k0 += 32) {
    GLD16(gA + k0, lA0);
    GLD16(gA + (size_t)64 * K + k0, lA1);
    GLD16(gB + k0, lB0);
    GLD16(gB + (size_t)64 * K + k0, lB1);
    __syncthreads();

    bf16x8 af[4], bf[4];
#pragma unroll
    for (int i = 0; i < 4; i++)
      af[i] = *(const bf16x8*)&As[(wm + i * 16 + fr) * 32 + fk];
#pragma unroll
    for (int j = 0; j < 4; j++)
      bf[j] = *(const bf16x8*)&Bs[(wn + j * 16 + fr) * 32 + fk];
#pragma unroll
    for (int i = 0; i < 4; i++)
#pragma unroll
      for (int j = 0; j < 4; j++)
        acc[i][j] =
            __builtin_amdgcn_mfma_f32_16x16x32_bf16(af[i], bf[j], acc[i][j], 0, 0, 0);
    __syncthreads();
  }

  // C/D layout: col = lane&15, row = (lane>>4)*4 + reg  [m89/m91 verified]
#pragma unroll
  for (int i = 0; i < 4; i++) {
    const int gm = m0 + wm + i * 16 + (lane >> 4) * 4;
#pragma unroll
    for (int j = 0; j < 4; j++) {
      const int gn = n0 + wn + j * 16 + fr;
#pragma unroll
      for (int rix = 0; rix < 4; rix++) {
        float val = acc[i][j][rix];
        val = apply_epi_f(epi, val, gn, gm + rix, N, bias, ex1, ex2);
        C[(size_t)(gm + rix) * N + gn] = val;
        if (C16) C16[(size_t)(gm + rix) * N + gn] = bf16b(val);
      }
    }
  }
}

// 128x64 tile, bf16 out (stage-1). N is the output row stride.
static __device__ __forceinline__ void gemm64_tile(
    const short* __restrict__ A, const short* __restrict__ Bw,
    short* __restrict__ out16, int M, int N, int K, int bx, int by, int epi,
    short* As, short* Bs) {
  const int tid = threadIdx.x;
  const int wave = tid >> 6, lane = tid & 63;
  const int m0 = by * 128, n0 = bx * 64;
  const int wm = (wave >> 1) * 64, wn = (wave & 1) * 32;
  const int fr = lane & 15, fk = (lane >> 4) * 8;

  f32x4 acc[4][2];
#pragma unroll
  for (int i = 0; i < 4; i++)
#pragma unroll
    for (int j = 0; j < 2; j++) acc[i][j] = (f32x4){0.f, 0.f, 0.f, 0.f};

  const int srow = tid >> 2, scol = (tid & 3) * 8;
  const short* gA = A + (size_t)(m0 + srow) * K + scol;
  const short* gB = Bw + (size_t)(n0 + srow) * K + scol;
  short* lA0 = &As[wave * 512];
  short* lA1 = &As[2048 + wave * 512];
  short* lB0 = &Bs[wave * 512];

  for (int k0 = 0; k0 < K; k0 += 32) {
    GLD16(gA + k0, lA0);
    GLD16(gA + (size_t)64 * K + k0, lA1);
    GLD16(gB + k0, lB0);
    __syncthreads();

    bf16x8 af[4], bf[2];
#pragma unroll
    for (int i = 0; i < 4; i++)
      af[i] = *(const bf16x8*)&As[(wm + i * 16 + fr) * 32 + fk];
#pragma unroll
    for (int j = 0; j < 2; j++)
      bf[j] = *(const bf16x8*)&Bs[(wn + j * 16 + fr) * 32 + fk];
#pragma unroll
    for (int i = 0; i < 4; i++)
#pragma unroll
      for (int j = 0; j < 2; j++)
        acc[i][j] =
            __builtin_amdgcn_mfma_f32_16x16x32_bf16(af[i], bf[j], acc[i][j], 0, 0, 0);
    __syncthreads();
  }

#pragma unroll
  for (int i = 0; i < 4; i++) {
    const int gm = m0 + wm + i * 16 + (lane >> 4) * 4;
#pragma unroll
    for (int j = 0; j < 2; j++) {
      const int gn = n0 + wn + j * 16 + fr;
#pragma unroll
      for (int rix = 0; rix < 4; rix++) {
        float val = acc[i][j][rix];
        if (epi == EPI_TANH) val = tanhf(val);
        else if (epi == EPI_SIGMOID) val = 1.f / (1.f + expf(-val));
        out16[(size_t)(gm + rix) * N + gn] = bf16b(val);
      }
    }
  }
}

// ---------------- merged GEMM kernels ----------------
__global__ __launch_bounds__(256) void big3_k(
    const short* __restrict__ xr, const short* __restrict__ xk,
    const short* __restrict__ xv, const short* __restrict__ wrb,
    const short* __restrict__ wkb, const short* __restrict__ wvb,
    float* __restrict__ r_, float* __restrict__ kbuf,
    float* __restrict__ vbuf, short* __restrict__ vbuf16) {
  __shared__ short smem[2 * 128 * 32];
  const int role = blockIdx.x / 6, bx = blockIdx.x % 6;
  const short* A;
  const short* Bw;
  float* C;
  short* C16 = nullptr;
  if (role == 0) { A = xr; Bw = wrb; C = r_; }
  else if (role == 1) { A = xk; Bw = wkb; C = kbuf; }
  else { A = xv; Bw = wvb; C = vbuf; C16 = vbuf16; }
  gemm128_tile(A, Bw, C, C16, B_ * T_, C_, C_, bx, blockIdx.y, EPI_NONE,
               nullptr, nullptr, nullptr, smem, smem + 128 * 32);
}

__global__ __launch_bounds__(256) void s1x4_k(
    const short* __restrict__ xw, const short* __restrict__ xa,
    const short* __restrict__ xg, const short* __restrict__ vbuf16,
    const short* __restrict__ wAT, const short* __restrict__ aAT,
    const short* __restrict__ gAT, const short* __restrict__ vAT,
    short* __restrict__ h_w, short* __restrict__ h_a,
    short* __restrict__ h_g, short* __restrict__ h_v) {
  __shared__ short smem[128 * 32 + 64 * 32];
  const int bx = blockIdx.x;  // 0..4
  const short* A;
  const short* Bw;
  short* O;
  int N, tb, epi;
  if (bx == 0)      { A = xw;     Bw = wAT; O = h_w; N = 64;  tb = 0; epi = EPI_TANH; }
  else if (bx == 1) { A = xa;     Bw = aAT; O = h_a; N = 64;  tb = 0; epi = EPI_NONE; }
  else if (bx == 2) { A = xg;     Bw = gAT; O = h_g; N = 128; tb = 0; epi = EPI_SIGMOID; }
  else if (bx == 3) { A = xg;     Bw = gAT; O = h_g; N = 128; tb = 1; epi = EPI_SIGMOID; }
  else              { A = vbuf16; Bw = vAT; O = h_v; N = 64;  tb = 0; epi = EPI_NONE; }
  gemm64_tile(A, Bw, O, B_ * T_, N, C_, tb, blockIdx.y, epi, smem,
              smem + 128 * 32);
}

__global__ __launch_bounds__(256) void s2x3_k(
    const short* __restrict__ h_v, const short* __restrict__ h_w,
    const short* __restrict__ h_a, const short* __restrict__ vBT,
    const short* __restrict__ wBT, const short* __restrict__ aBT,
    float* __restrict__ vbuf, float* __restrict__ dec_, float* __restrict__ a_,
    const float* __restrict__ v_miu, const float* __restrict__ w_miu,
    const float* __restrict__ a_miu, const float* __restrict__ v_first) {
  __shared__ short smem[2 * 128 * 32];
  const int role = blockIdx.x / 6, bx = blockIdx.x % 6;
  const short* A;
  const short* Bw;
  float* C;
  const float* bias;
  const float* ex1 = nullptr;
  const float* ex2 = nullptr;
  int epi;
  if (role == 0) { A = h_v; Bw = vBT; C = vbuf; bias = v_miu; ex1 = vbuf; ex2 = v_first; epi = EPI_VMIX; }
  else if (role == 1) { A = h_w; Bw = wBT; C = dec_; bias = w_miu; epi = EPI_WDECAY; }
  else { A = h_a; Bw = aBT; C = a_; bias = a_miu; epi = EPI_SIGBIAS; }
  gemm128_tile(A, Bw, C, nullptr, B_ * T_, C_, 64, bx, blockIdx.y, epi, bias,
               ex1, ex2, smem, smem + 128 * 32);
}

__global__ __launch_bounds__(256) void outp_k(
    const short* __restrict__ ymb, const short* __restrict__ wob,
    float* __restrict__ out) {
  __shared__ short smem[2 * 128 * 32];
  gemm128_tile(ymb, wob, out, nullptr, B_ * T_, C_, C_, blockIdx.x,
               blockIdx.y, EPI_NONE, nullptr, nullptr, nullptr, smem,
               smem + 128 * 32);
}

// ---------------- mix -> bf16 (6 lambdas, one pass) ----------------
__global__ __launch_bounds__(256) void mix6_k(
    const float* __restrict__ x, const float* __restrict__ lr,
    const float* __restrict__ lk, const float* __restrict__ lv,
    const float* __restrict__ lw, const float* __restrict__ la,
    const float* __restrict__ lg, short* __restrict__ xr,
    short* __restrict__ xk, short* __restrict__ xv, short* __restrict__ xw,
    short* __restrict__ xa, short* __restrict__ xg) {
  const int i = blockIdx.x * 256 + threadIdx.x;  // float4 index
  const int c4 = i % (C_ / 4);
  const int gm = i / (C_ / 4);
  const float4 xa4 = ((const float4*)x)[i];
  float4 xp = make_float4(0.f, 0.f, 0.f, 0.f);
  if ((gm % T_) != 0) xp = ((const float4*)x)[i - C_ / 4];
  const float4 dx =
      make_float4(xp.x - xa4.x, xp.y - xa4.y, xp.z - xa4.z, xp.w - xa4.w);

#define MIXOUT(dst, lam)                                                      \
  {                                                                           \
    const float4 l4 = ((const float4*)lam)[c4];                               \
    short4 o = {bf16b(fmaf(dx.x, l4.x, xa4.x)),                               \
                bf16b(fmaf(dx.y, l4.y, xa4.y)),                               \
                bf16b(fmaf(dx.z, l4.z, xa4.z)),                               \
                bf16b(fmaf(dx.w, l4.w, xa4.w))};                              \
    ((short4*)dst)[i] = o;                                                    \
  }
  MIXOUT(xr, lr);
  MIXOUT(xk, lk);
  MIXOUT(xv, lv);
  MIXOUT(xw, lw);
  MIXOUT(xa, la);
  MIXOUT(xg, lg);
#undef MIXOUT
}

// ------------- weights prep: 4 straight converts + 8 transposes ----------
__global__ __launch_bounds__(256) void wprep_k(
    const float* __restrict__ W_r, const float* __restrict__ W_k,
    const float* __restrict__ W_v, const float* __restrict__ W_o,
    const float* __restrict__ w_A, const float* __restrict__ a_A,
    const float* __restrict__ v_A, const float* __restrict__ g_A,
    const float* __restrict__ w_B, const float* __restrict__ a_B,
    const float* __restrict__ v_B, const float* __restrict__ g_B,
    short* __restrict__ wrb, short* __restrict__ wkb,
    short* __restrict__ wvb, short* __restrict__ wob,
    short* __restrict__ wAT, short* __restrict__ aAT,
    short* __restrict__ vAT, short* __restrict__ gAT,
    short* __restrict__ wBT, short* __restrict__ aBT,
    short* __restrict__ vBT, short* __restrict__ gBT) {
  const int job = blockIdx.y;
  const int WN = C_ * C_;
  if (job < 4) {
    const float* src = (job == 0) ? W_r : (job == 1) ? W_k : (job == 2) ? W_v : W_o;
    short* dst = (job == 0) ? wrb : (job == 1) ? wkb : (job == 2) ? wvb : wob;
    const int n4 = WN / 4;
    for (int i = blockIdx.x * 256 + threadIdx.x; i < n4; i += gridDim.x * 256) {
      const float4 v = ((const float4*)src)[i];
      short4 o = {bf16b(v.x), bf16b(v.y), bf16b(v.z), bf16b(v.w)};
      ((short4*)dst)[i] = o;
    }
  } else {
    const float* in;
    short* out;
    int R, Cc;
    switch (job) {
      case 4: in = w_A; out = wAT; R = C_; Cc = 64; break;
      case 5: in = a_A; out = aAT; R = C_; Cc = 64; break;
      case 6: in = v_A; out = vAT; R = C_; Cc = 64; break;
      case 7: in = g_A; out = gAT; R = C_; Cc = 128; break;
      case 8: in = w_B; out = wBT; R = 64; Cc = C_; break;
      case 9: in = a_B; out = aBT; R = 64; Cc = C_; break;
      case 10: in = v_B; out = vBT; R = 64; Cc = C_; break;
      default: in = g_B; out = gBT; R = 128; Cc = C_; break;
    }
    const int n = R * Cc;
    for (int i = blockIdx.x * 256 + threadIdx.x; i < n; i += gridDim.x * 256) {
      const int r = i / Cc, c = i % Cc;
      out[(size_t)c * R + r] = bf16b(in[i]);
    }
  }
}

// ---------------- kk prep ----------------
__global__ __launch_bounds__(256) void kkprep_k(
    const float* __restrict__ k0, const float* __restrict__ a,
    const float* __restrict__ k_k, const float* __restrict__ k_a,
    float* __restrict__ kout, float* __restrict__ z, float* __restrict__ bb) {
  const int wid = threadIdx.x >> 6;
  const int lane = threadIdx.x & 63;
  const size_t hid = (size_t)blockIdx.x * 4 + wid;
  const int h = (int)(hid % H_);
  const size_t idx = hid * 64 + lane;
  const int c = h * 64 + lane;
  const float kv = k0[idx];
  const float av = a[idx];
  const float kk = kv * k_k[c];
  const float ss = wave_sum64(kk * kk);
  const float denom = fmaxf(sqrtf(ss), 1e-12f);
  const float kkn = kk / denom;
  z[idx] = -kkn;
  bb[idx] = kkn * av;
  kout[idx] = kv * (1.f + (av - 1.f) * k_a[c]);
}

// ---------------- fused WKV-7 + stage2-g GEMM + v_first copy -------------
// 256 blocks x 256 threads. Blocks 0..191: R5-structure recurrence with v in
// chunk-ahead global-prefetched registers (5 LDS streams, 40KB). Blocks
// 192..239: persistent stage2-g GEMM (8 tiles each). Blocks 240..255: copy.
#define CH 16
#define NC (T_ / CH)
__global__ __launch_bounds__(256) void wkv7f_k(
    const float* __restrict__ rr, const float* __restrict__ dd,
    const float* __restrict__ kk, const float* __restrict__ vv,
    const float* __restrict__ zz, const float* __restrict__ bbv,
    float* __restrict__ yy, const short* __restrict__ h_g,
    const short* __restrict__ gBT, float* __restrict__ g_,
    const float4* __restrict__ cpsrc, float4* __restrict__ cpdst, int n4) {
  __shared__ __align__(16) char smem[2 * 5 * CH * 64 * 4];  // 40 KB
  const int blk = blockIdx.x;

  if (blk >= 240) {  // ---- copy role ----
    const int rb = blk - 240;
    for (int i = rb * 256 + threadIdx.x; i < n4; i += 16 * 256)
      cpdst[i] = cpsrc[i];
    return;
  }
  if (blk >= 192) {  // ---- stage2-g GEMM role (persistent, 8 tiles) ----
    short* As = (short*)smem;
    short* Bs = As + 128 * 32;
    const int rb = blk - 192;
    for (int it = 0; it < 8; ++it) {
      const int tile = rb + it * 48;  // 0..383
      gemm128_tile(h_g, gBT, g_, nullptr, B_ * T_, C_, 128, tile % 6,
                   tile / 6, EPI_NONE, nullptr, nullptr, nullptr, As, Bs);
    }
    return;
  }

  // ---- wkv7 role ----
  float* lds = (float*)smem;  // [2][5*CH*64]
  const int bh = blk % 48;
  const int rq = blk / 48;
  const int b = bh / H_, h = bh % H_;
  const int tid = threadIdx.x;
  const int wave = tid >> 6;
  const int l = tid & 63;
  const int l16 = l & 15;
  const int row = rq * 16 + wave * 4 + (l >> 4);
  const int cb = l16 * 4;
  const size_t btb = (size_t)b * T_;

  const size_t g0 = (btb + wave * 4 + (l >> 4)) * C_ + h * 64 + cb;
  const int dbase = wave * 256;  // floats: 4 steps * 64
  const size_t vrow0 = btb * C_ + h * 64 + row;

#define STAGE(BUF, GOFF)                                                      \
  {                                                                           \
    float* Ld = lds + (BUF) * 5120;                                           \
    GLD16(dd + (GOFF), Ld + 0 * 1024 + dbase);                                \
    GLD16(zz + (GOFF), Ld + 1 * 1024 + dbase);                                \
    GLD16(bbv + (GOFF), Ld + 2 * 1024 + dbase);                               \
    GLD16(kk + (GOFF), Ld + 3 * 1024 + dbase);                                \
    GLD16(rr + (GOFF), Ld + 4 * 1024 + dbase);                                \
  }

#define LDSTEP(S_, TL_)                                                       \
  {                                                                           \
    Wf[S_] = *(const float4*)&Lb[0 * 1024 + (TL_) * 64 + cb];                 \
    Zf[S_] = *(const float4*)&Lb[1 * 1024 + (TL_) * 64 + cb];                 \
    Bf[S_] = *(const float4*)&Lb[2 * 1024 + (TL_) * 64 + cb];                 \
    Kf[S_] = *(const float4*)&Lb[3 * 1024 + (TL_) * 64 + cb];                 \
    Rf[S_] = *(const float4*)&Lb[4 * 1024 + (TL_) * 64 + cb];                 \
  }

#define PREFV(ARR, CC)                                                        \
  {                                                                           \
    const size_t vb = vrow0 + (size_t)(CC) * CH * C_;                         \
    _Pragma("unroll") for (int j = 0; j < CH; ++j)                            \
        ARR[j] = vv[vb + (size_t)j * C_];                                     \
  }

#define CHUNK_BODY(VARR, CIDX)                                                \
  {                                                                           \
    float4 Wf[3], Zf[3], Bf[3], Kf[3], Rf[3];                                 \
    LDSTEP(0, 0);                                                             \
    LDSTEP(1, 1);                                                             \
    _Pragma("unroll") for (int tl = 0; tl < CH; ++tl) {                       \
      const int sl = tl % 3;                                                  \
      if (tl + 2 < CH) { LDSTEP((tl + 2) % 3, tl + 2); }                      \
      const float4 w4 = Wf[sl], z4 = Zf[sl], b4 = Bf[sl], k4 = Kf[sl],        \
                   r4 = Rf[sl];                                               \
      const float vi = VARR[tl];                                              \
      float sa = fmaf(S1, z4.y, S0 * z4.x) + fmaf(S3, z4.w, S2 * z4.z);       \
      sa = row_sum16(sa);                                                     \
      S0 = fmaf(S0, w4.x, fmaf(sa, b4.x, vi * k4.x));                         \
      S1 = fmaf(S1, w4.y, fmaf(sa, b4.y, vi * k4.y));                         \
      S2 = fmaf(S2, w4.z, fmaf(sa, b4.z, vi * k4.z));                         \
      S3 = fmaf(S3, w4.w, fmaf(sa, b4.w, vi * k4.w));                         \
      float yp = fmaf(S1, r4.y, S0 * r4.x) + fmaf(S3, r4.w, S2 * r4.z);       \
      yp = row_sum16(yp);                                                     \
      if (l16 == 0) yy[ybase + (size_t)((CIDX)*CH + tl) * C_] = yp;           \
    }                                                                         \
  }

  float vA[CH], vB[CH];
  STAGE(0, g0);
  PREFV(vA, 0);
  __syncthreads();

  float S0 = 0.f, S1 = 0.f, S2 = 0.f, S3 = 0.f;
  size_t gpf = g0 + (size_t)CH * C_;
  const size_t ybase = btb * C_ + h * 64 + row;

  for (int c = 0; c < NC; c += 2) {
    // even chunk c (buf0): consume vA; prefetch vB for c+1; stage c+1
    PREFV(vB, c + 1);
    STAGE(1, gpf);
    gpf += (size_t)CH * C_;
    {
      const float* Lb = lds;
      CHUNK_BODY(vA, c)
    }
    __syncthreads();
    // odd chunk c+1 (buf1): consume vB; prefetch vA for c+2; stage c+2
    {
      const int cn = (c + 2 < NC) ? (c + 2) : (NC - 1);
      PREFV(vA, cn);
    }
    if (c + 2 < NC) STAGE(0, gpf);
    gpf += (size_t)CH * C_;
    {
      const float* Lb = lds + 5120;
      CHUNK_BODY(vB, c + 1)
    }
    __syncthreads();
  }
#undef STAGE
#undef LDSTEP
#undef PREFV
#undef CHUNK_BODY
}

// ---------------- GroupNorm + r_k term + g gating -> bf16 ----------------
__global__ __launch_bounds__(256) void gn_k(
    const float* __restrict__ y, const float* __restrict__ r,
    const float* __restrict__ k, const float* __restrict__ v,
    const float* __restrict__ g, const float* __restrict__ r_k,
    const float* __restrict__ ln_w, const float* __restrict__ ln_b,
    short* __restrict__ ymb) {
  const int wid = threadIdx.x >> 6;
  const int lane = threadIdx.x & 63;
  const size_t hid = (size_t)blockIdx.x * 4 + wid;
  const int h = (int)(hid % H_);
  const size_t idx = hid * 64 + lane;
  const int c = h * 64 + lane;

  const float yv = y[idx];
  const float mu = wave_sum64(yv) * (1.f / 64.f);
  const float sq = wave_sum64(yv * yv) * (1.f / 64.f);
  const float var = sq - mu * mu;
  float yn = (yv - mu) * rsqrtf(var + 0.00064f);
  yn = yn * ln_w[c] + ln_b[c];

  const float s = wave_sum64(r[idx] * k[idx] * r_k[c]);
  yn += s * v[idx];
  ymb[idx] = bf16b(yn * g[idx]);
}

// ---------------- host launcher ----------------
extern "C" void kernel_launch(void* const* d_in, const int* in_sizes, int n_in,
                              void* d_out, int out_size, void* d_ws,
                              size_t ws_size, hipStream_t stream) {
  const float* x       = (const float*)d_in[0];
  const float* v_first = (const float*)d_in[1];
  const float* lam_r   = (const float*)d_in[2];
  const float* lam_w   = (const float*)d_in[3];
  const float* lam_k   = (const float*)d_in[4];
  const float* lam_v   = (const float*)d_in[5];
  const float* lam_a   = (const float*)d_in[6];
  const float* lam_g   = (const float*)d_in[7];
  const float* w_miu   = (const float*)d_in[8];
  const float* w_A     = (const float*)d_in[9];
  const float* w_B     = (const float*)d_in[10];
  const float* a_miu   = (const float*)d_in[11];
  const float* a_A     = (const float*)d_in[12];
  const float* a_B     = (const float*)d_in[13];
  const float* v_miu   = (const float*)d_in[14];
  const float* v_A     = (const float*)d_in[15];
  const float* v_B     = (const float*)d_in[16];
  const float* g_A     = (const float*)d_in[17];
  const float* g_B     = (const float*)d_in[18];
  const float* k_k     = (const float*)d_in[19];
  const float* k_a     = (const float*)d_in[20];
  const float* r_k     = (const float*)d_in[21];
  const float* W_r     = (const float*)d_in[22];
  const float* W_k     = (const float*)d_in[23];
  const float* W_v     = (const float*)d_in[24];
  const float* W_o     = (const float*)d_in[25];
  const float* ln_w    = (const float*)d_in[26];
  const float* ln_b    = (const float*)d_in[27];

  const int M = B_ * T_;            // 8192
  const size_t S = (size_t)M * C_;  // 6291456

  float* ws   = (float*)d_ws;
  float* r_   = ws + 0 * S;
  float* kbuf = ws + 1 * S;
  float* vbuf = ws + 2 * S;
  float* dec_ = ws + 3 * S;
  float* a_   = ws + 4 * S;
  float* g_   = ws + 5 * S;
  float* z_   = ws + 6 * S;
  float* bb_  = ws + 7 * S;
  float* h_   = ws + 8 * S;                       // M*128 floats (stage-1 hs)
  short* wb   = (short*)(h_ + (size_t)M * 128);   // bf16 weight copies
  float* out  = (float*)d_out;

  const int WN = C_ * C_;  // 589824
  short* wrb = wb + 0 * (size_t)WN;
  short* wkb = wb + 1 * (size_t)WN;
  short* wvb = wb + 2 * (size_t)WN;
  short* wob = wb + 3 * (size_t)WN;
  short* wAT = wb + 4 * (size_t)WN;
  short* aAT = wAT + (size_t)C_ * 64;
  short* vAT = aAT + (size_t)C_ * 64;
  short* gAT = vAT + (size_t)C_ * 64;
  short* wBT = gAT + (size_t)C_ * 128;
  short* aBT = wBT + (size_t)C_ * 64;
  short* vBT = aBT + (size_t)C_ * 64;
  short* gBT = vBT + (size_t)C_ * 64;

  // bf16 aliases in dead fp32 slots
  short* xr  = (short*)dec_;          // consumed (big3) before dec_ written
  short* xk  = (short*)a_;            // consumed (big3) before a_ written
  short* xv  = (short*)g_;            // consumed (big3) before h_v written
  short* xw  = (short*)z_;            // consumed (s1) before kkprep writes z_
  short* xa  = (short*)z_ + S;        // second half of z_ slot
  short* xg  = (short*)bb_;           // consumed (s1) before kkprep writes bb_
  short* vbuf16 = (short*)bb_ + S;    // second half of bb_ slot
  short* h_w = (short*)h_;            // M*64
  short* h_a = h_w + (size_t)M * 64;  // M*64
  short* h_g = h_a + (size_t)M * 64;  // M*128
  short* h_v = (short*)g_;            // g_ slot first M*64 shorts; written by
                                      // s1 (after xv dead), read by s2-VMIX,
                                      // dead before wkv7f's s2g writes g_
  short* ymb = (short*)z_;            // written by gn after wkv7 consumed z_

  // 1) weights prep (12 jobs, one launch)
  {
    dim3 blk(256), grid(576, 12);
    hipLaunchKernelGGL(wprep_k, grid, blk, 0, stream, W_r, W_k, W_v, W_o,
                       w_A, a_A, v_A, g_A, w_B, a_B, v_B, g_B, wrb, wkb, wvb,
                       wob, wAT, aAT, vAT, gAT, wBT, aBT, vBT, gBT);
  }
  // 2) mixed x -> bf16, all 6 lambdas
  {
    dim3 blk(256), grid((int)(S / 4 / 256));
    hipLaunchKernelGGL(mix6_k, grid, blk, 0, stream, x, lam_r, lam_k, lam_v,
                       lam_w, lam_a, lam_g, xr, xk, xv, xw, xa, xg);
  }
  // 3) big projections r/k/v (one launch; v dual-writes bf16)
  {
    dim3 blk(256), grid(18, M / 128);
    hipLaunchKernelGGL(big3_k, grid, blk, 0, stream, xr, xk, xv, wrb, wkb,
                       wvb, r_, kbuf, vbuf, vbuf16);
  }
  // 4) stage-1 low-rank projections (one launch, fused activations)
  {
    dim3 blk(256), grid(5, M / 128);
    hipLaunchKernelGGL(s1x4_k, grid, blk, 0, stream, xw, xa, xg, vbuf16, wAT,
                       aAT, gAT, vAT, h_w, h_a, h_g, h_v);
  }
  // 5) stage-2 expansions VMIX/WDECAY/SIGBIAS (one launch)
  {
    dim3 blk(256), grid(18, M / 128);
    hipLaunchKernelGGL(s2x3_k, grid, blk, 0, stream, h_v, h_w, h_a, vBT, wBT,
                       aBT, vbuf, dec_, a_, v_miu, w_miu, a_miu, v_first);
  }
  // 6) kk prep
  {
    dim3 grid((B_ * T_ * H_) / 4), blk(256);
    hipLaunchKernelGGL(kkprep_k, grid, blk, 0, stream, kbuf, a_, k_k, k_a,
                       kbuf, z_, bb_);
  }
  // 7) fused recurrence + stage2-g GEMM + v_first copy (256 blocks)
  {
    dim3 grid(256), blk(256);
    hipLaunchKernelGGL(wkv7f_k, grid, blk, 0, stream, r_, dec_, kbuf, vbuf,
                       z_, bb_, a_, h_g, gBT, g_, (const float4*)v_first,
                       (float4*)(out + S), (int)(S / 4));
  }
  // 8) groupnorm + rk-term + gate -> ymb
  {
    dim3 grid((B_ * T_ * H_) / 4), blk(256);
    hipLaunchKernelGGL(gn_k, grid, blk, 0, stream, a_, r_, kbuf, vbuf, g_, r_k,
                       ln_w, ln_b, ymb);
  }
  // 9) output projection
  {
    dim3 blk(256), grid(C_ / 128, M / 128);
    hipLaunchKernelGGL(outp_k, grid, blk, 0, stream, ymb, wob, out);
  }
}